// Round 3
// baseline (674.633 us; speedup 1.0000x reference)
//
#include <hip/hip_runtime.h>
#include <math.h>

#define B_ 32
#define DIM_ 4096
#define NKV_ 8
#define HD_ 128
#define T_ 2048
#define KS_ 16
#define QKV_ROWS_ 6144
#define O_ROWS_ 4096
#define NSPLITW_ 64         // splits per (b,kv): 16 chunks * 4 waves

// ws layout (float offsets)
#define Q_OFF    0
#define KNEW_OFF (Q_OFF + B_*DIM_)
#define VNEW_OFF (KNEW_OFF + B_*NKV_*HD_)
#define AO_OFF   (VNEW_OFF + B_*NKV_*HD_)
#define PQKV_OFF (AO_OFF + B_*DIM_)
#define PO_OFF   (PQKV_OFF + KS_*QKV_ROWS_*B_)
#define OPART_OFF (PO_OFF + KS_*O_ROWS_*B_)
#define ML_OFF   (OPART_OFF + B_*NKV_*NSPLITW_*4*HD_)
// ML: B*NKV*64 splits*4 reps*2 floats

__device__ __forceinline__ void fma4(float4& a, const float4& x, float w) {
    a.x = fmaf(x.x, w, a.x); a.y = fmaf(x.y, w, a.y);
    a.z = fmaf(x.z, w, a.z); a.w = fmaf(x.w, w, a.w);
}

// C[b][row] partial = sum_{k in chunk} X[b][k] * W[row][k]
// register double-buffer: tile kt+1 loads issue before compute of kt
template<int NROWS>
__global__ __launch_bounds__(256) void gemm_split(
    const float* __restrict__ X, const float* __restrict__ W0,
    const float* __restrict__ W1, const float* __restrict__ W2,
    float* __restrict__ part)
{
    __shared__ float xs[32][36];
    __shared__ float wsh[32][132];
    const int rb = blockIdx.x, ks = blockIdx.y;
    const int row0 = rb * 128;
    const float* W; int wr0;
    if (NROWS == 4096 || row0 < 4096) { W = W0; wr0 = row0; }
    else if (row0 < 5120)             { W = W1; wr0 = row0 - 4096; }
    else                              { W = W2; wr0 = row0 - 5120; }
    const int tid = threadIdx.x;
    const int rt = tid & 31, bt = tid >> 5;
    float4 acc[4];
    acc[0] = acc[1] = acc[2] = acc[3] = make_float4(0.f,0.f,0.f,0.f);
    const int kc0 = ks * 256;
    const int xb = tid >> 3, xkq = tid & 7;   // xb doubles as W row base
    float4 xpf, wpf[4];
    xpf = *(const float4*)(X + xb * DIM_ + kc0 + xkq * 4);
    #pragma unroll
    for (int j = 0; j < 4; ++j)
        wpf[j] = *(const float4*)(W + (wr0 + xb + 32*j) * DIM_ + kc0 + xkq * 4);
    for (int kt = 0; kt < 8; ++kt) {
        __syncthreads();
        xs[xkq*4+0][xb] = xpf.x; xs[xkq*4+1][xb] = xpf.y;
        xs[xkq*4+2][xb] = xpf.z; xs[xkq*4+3][xb] = xpf.w;
        #pragma unroll
        for (int j = 0; j < 4; ++j) {
            const int r = xb + 32*j;
            wsh[xkq*4+0][r] = wpf[j].x; wsh[xkq*4+1][r] = wpf[j].y;
            wsh[xkq*4+2][r] = wpf[j].z; wsh[xkq*4+3][r] = wpf[j].w;
        }
        __syncthreads();
        if (kt < 7) {
            const int kc = kc0 + (kt + 1) * 32;
            xpf = *(const float4*)(X + xb * DIM_ + kc + xkq * 4);
            #pragma unroll
            for (int j = 0; j < 4; ++j)
                wpf[j] = *(const float4*)(W + (wr0 + xb + 32*j) * DIM_ + kc + xkq * 4);
        }
        #pragma unroll
        for (int k = 0; k < 32; ++k) {
            float4 xv = *(const float4*)&xs[k][bt*4];
            float4 wv = *(const float4*)&wsh[k][rt*4];
            fma4(acc[0], xv, wv.x);
            fma4(acc[1], xv, wv.y);
            fma4(acc[2], xv, wv.z);
            fma4(acc[3], xv, wv.w);
        }
    }
    #pragma unroll
    for (int j = 0; j < 4; ++j) {
        const int row = row0 + rt * 4 + j;
        *(float4*)(part + (ks * NROWS + row) * 32 + bt * 4) = acc[j];
    }
}

__global__ __launch_bounds__(256) void reduce_rope(
    const float* __restrict__ part, const float* __restrict__ fc,
    const float* __restrict__ fs, float* __restrict__ qout,
    float* __restrict__ kout, float* __restrict__ vout)
{
    const int t = blockIdx.x * 256 + threadIdx.x;
    const int b = t & 31;
    const int row0 = (t >> 5) * 2;
    float s0 = 0.f, s1 = 0.f;
    #pragma unroll
    for (int ks = 0; ks < KS_; ++ks) {
        const float* p = part + (ks * QKV_ROWS_ + row0) * 32 + b;
        s0 += p[0];
        s1 += p[32];
    }
    if (row0 < 5120) {
        const int i = (row0 & 127) >> 1;
        const float c = fc[i], s = fs[i];
        const float o0 = s0 * c - s1 * s;
        const float o1 = s0 * s + s1 * c;
        if (row0 < 4096) {
            qout[b * 4096 + row0]     = o0;
            qout[b * 4096 + row0 + 1] = o1;
        } else {
            const int lr = row0 - 4096;
            kout[b * 1024 + lr]     = o0;
            kout[b * 1024 + lr + 1] = o1;
        }
    } else {
        const int lr = row0 - 5120;
        vout[b * 1024 + lr]     = s0;
        vout[b * 1024 + lr + 1] = s1;
    }
}

// decode attention, contiguity + occupancy:
// block = (b, 128-t chunk, kv-half of 4 heads) -> grid 1024, 4 blocks/CU.
// Per t the block reads a contiguous 2 KB sub-row of cache_k/cache_v.
// Wave owns a private 32-t sub-split (own m,l,Opart).
// lane = (kvl = ln>>4 in 0..3, dsl = ln&15): 8 d-floats per lane.
__global__ __launch_bounds__(256, 4) void attn_split(
    const float* __restrict__ q, const float* __restrict__ knew,
    const float* __restrict__ vnew, const float* __restrict__ ck,
    const float* __restrict__ cv, float* __restrict__ opart,
    float* __restrict__ ml)
{
    __shared__ float sct[4][16 * 33];   // per-wave [pair=kvl*4+rep][33] scores/probs
    const int kvh   = blockIdx.x & 1;
    const int chunk = (blockIdx.x >> 1) & 15;
    const int b     = blockIdx.x >> 5;
    const int tid = threadIdx.x;
    const int w  = tid >> 6, ln = tid & 63;
    const int kvl = ln >> 4, dsl = ln & 15;
    const int kv  = kvh * 4 + kvl;
    const int t0 = chunk * 128 + w * 32;
    const int split = chunk * 4 + w;
    const float scale = 0.08838834764831845f;  // 128^-0.5
    float* ss = sct[w];

    // ---- phase A: scores for this wave's 32 t, 4 kv heads x 4 reps ----
    float4 qr[4][2];
    #pragma unroll
    for (int r = 0; r < 4; ++r) {
        const float* qp = q + b * 4096 + (kv * 4 + r) * 128 + dsl * 8;
        qr[r][0] = *(const float4*)qp;
        qr[r][1] = *(const float4*)(qp + 4);
    }
    const float* ckb = ck + (size_t)b * (2048 * 1024) + kv * 128 + dsl * 8;
    const float* knb = knew + (b * 8 + kv) * 128 + dsl * 8;

    for (int tt = 0; tt < 32; tt += 4) {
        float4 ka[4][2];
        #pragma unroll
        for (int u = 0; u < 4; ++u) {
            const int gt = t0 + tt + u;
            const float* kp = (gt == 2047) ? knb : (ckb + (size_t)gt * 1024);
            ka[u][0] = *(const float4*)kp;
            ka[u][1] = *(const float4*)(kp + 4);
        }
        #pragma unroll
        for (int u = 0; u < 4; ++u) {
            float d[4];
            #pragma unroll
            for (int r = 0; r < 4; ++r) {
                float s = 0.f;
                s = fmaf(ka[u][0].x, qr[r][0].x, s);
                s = fmaf(ka[u][0].y, qr[r][0].y, s);
                s = fmaf(ka[u][0].z, qr[r][0].z, s);
                s = fmaf(ka[u][0].w, qr[r][0].w, s);
                s = fmaf(ka[u][1].x, qr[r][1].x, s);
                s = fmaf(ka[u][1].y, qr[r][1].y, s);
                s = fmaf(ka[u][1].z, qr[r][1].z, s);
                s = fmaf(ka[u][1].w, qr[r][1].w, s);
                s += __shfl_xor(s, 1);
                s += __shfl_xor(s, 2);
                s += __shfl_xor(s, 4);
                s += __shfl_xor(s, 8);
                d[r] = s * scale;
            }
            // lanes dsl=0..3 store rep dsl; banks (kvl*4+dsl) all distinct
            float out = d[0];
            if (dsl == 1) out = d[1];
            if (dsl == 2) out = d[2];
            if (dsl == 3) out = d[3];
            if (dsl < 4) ss[(kvl * 4 + dsl) * 33 + tt + u] = out;
        }
    }
    __syncthreads();

    // ---- phase B: per-wave partial softmax, 32 lanes (2 per pair) ----
    if (ln < 32) {
        const int pr = ln >> 1, hf = ln & 1;
        float* row = ss + pr * 33 + hf * 16;
        float mx = row[0];
        #pragma unroll
        for (int t = 1; t < 16; ++t) mx = fmaxf(mx, row[t]);
        mx = fmaxf(mx, __shfl_xor(mx, 1));
        float sum = 0.f;
        #pragma unroll
        for (int t = 0; t < 16; ++t) {
            const float p = __expf(row[t] - mx);
            row[t] = p;
            sum += p;
        }
        sum += __shfl_xor(sum, 1);
        if (hf == 0) {
            const int kvg = kvh * 4 + (pr >> 2), rp = pr & 3;
            *(float2*)(ml + (size_t)(((b * 8 + kvg) * 64 + split) * 4 + rp) * 2)
                = make_float2(mx, sum);
        }
    }
    __syncthreads();

    // ---- phase C: partial O = P V, contiguous V stream ----
    float4 acc[4][2];
    #pragma unroll
    for (int r = 0; r < 4; ++r) {
        acc[r][0] = make_float4(0.f,0.f,0.f,0.f);
        acc[r][1] = make_float4(0.f,0.f,0.f,0.f);
    }
    const float* cvb = cv + (size_t)b * (2048 * 1024) + kv * 128 + dsl * 8;
    const float* vnb = vnew + (b * 8 + kv) * 128 + dsl * 8;
    for (int tt = 0; tt < 32; tt += 4) {
        float4 va[4][2];
        #pragma unroll
        for (int u = 0; u < 4; ++u) {
            const int gt = t0 + tt + u;
            const float* vp = (gt == 2047) ? vnb : (cvb + (size_t)gt * 1024);
            va[u][0] = *(const float4*)vp;
            va[u][1] = *(const float4*)(vp + 4);
        }
        #pragma unroll
        for (int u = 0; u < 4; ++u) {
            #pragma unroll
            for (int r = 0; r < 4; ++r) {
                const float p = ss[(kvl * 4 + r) * 33 + tt + u];  // 16-lane bcast
                fma4(acc[r][0], va[u][0], p);
                fma4(acc[r][1], va[u][1], p);
            }
        }
    }
    float* ob = opart + (size_t)(((b * 8 + kv) * 64 + split) * 4) * 128 + dsl * 8;
    #pragma unroll
    for (int r = 0; r < 4; ++r) {
        *(float4*)(ob + r * 128)     = acc[r][0];
        *(float4*)(ob + r * 128 + 4) = acc[r][1];
    }
}

// merge 64 sub-splits with log-sum-exp weights
__global__ __launch_bounds__(128) void attn_merge(
    const float* __restrict__ opart, const float* __restrict__ ml,
    float* __restrict__ ao)
{
    const int bk = blockIdx.x;          // b*8+kv
    const int tid = threadIdx.x;
    const int r = tid >> 5, dq = tid & 31;
    float M = -1e30f;
    #pragma unroll 8
    for (int sp = 0; sp < NSPLITW_; ++sp)
        M = fmaxf(M, ml[(size_t)((bk * 64 + sp) * 4 + r) * 2]);
    float L = 0.f;
    float4 o = make_float4(0.f, 0.f, 0.f, 0.f);
    #pragma unroll 4
    for (int sp = 0; sp < NSPLITW_; ++sp) {
        const float2 mlv = *(const float2*)(ml + (size_t)((bk * 64 + sp) * 4 + r) * 2);
        const float wgt = __expf(mlv.x - M);
        L += mlv.y * wgt;
        const float4 v = *(const float4*)(opart
            + (size_t)((bk * 64 + sp) * 4 + r) * 128 + dq * 4);
        fma4(o, v, wgt);
    }
    const float inv = 1.f / L;
    o.x *= inv; o.y *= inv; o.z *= inv; o.w *= inv;
    *(float4*)(ao + bk * 512 + r * 128 + dq * 4) = o;
}

__global__ __launch_bounds__(256) void reduce_out(
    const float* __restrict__ part, float* __restrict__ out)
{
    const int t = blockIdx.x * 256 + threadIdx.x;
    const int b = t & 31, row = t >> 5;
    float s = 0.f;
    #pragma unroll
    for (int ks = 0; ks < KS_; ++ks)
        s += part[(ks * O_ROWS_ + row) * 32 + b];
    out[b * 4096 + row] = s;
}

extern "C" void kernel_launch(void* const* d_in, const int* in_sizes, int n_in,
                              void* d_out, int out_size, void* d_ws, size_t ws_size,
                              hipStream_t stream)
{
    const float* x  = (const float*)d_in[0];
    const float* fc = (const float*)d_in[1];
    const float* fs = (const float*)d_in[2];
    const float* wq = (const float*)d_in[3];
    const float* wk = (const float*)d_in[4];
    const float* wv = (const float*)d_in[5];
    const float* wo = (const float*)d_in[6];
    const float* ck = (const float*)d_in[7];
    const float* cv = (const float*)d_in[8];
    float* ws    = (float*)d_ws;
    float* q     = ws + Q_OFF;
    float* knew  = ws + KNEW_OFF;
    float* vnew  = ws + VNEW_OFF;
    float* ao    = ws + AO_OFF;
    float* pqkv  = ws + PQKV_OFF;
    float* po    = ws + PO_OFF;
    float* opart = ws + OPART_OFF;
    float* mlp   = ws + ML_OFF;

    gemm_split<QKV_ROWS_><<<dim3(48, 16), 256, 0, stream>>>(x, wq, wk, wv, pqkv);
    reduce_rope<<<384, 256, 0, stream>>>(pqkv, fc, fs, q, knew, vnew);
    attn_split<<<1024, 256, 0, stream>>>(q, knew, vnew, ck, cv, opart, mlp);
    attn_merge<<<256, 128, 0, stream>>>(opart, mlp, ao);
    gemm_split<O_ROWS_><<<dim3(32, 16), 256, 0, stream>>>(ao, wo, wo, wo, po);
    reduce_out<<<512, 256, 0, stream>>>(po, (float*)d_out);
}

// Round 5
// 649.201 us; speedup vs baseline: 1.0392x; 1.0392x over previous
//
#include <hip/hip_runtime.h>
#include <math.h>

#define B_ 32
#define DIM_ 4096
#define NKV_ 8
#define HD_ 128
#define T_ 2048
#define KS_ 16
#define QKV_ROWS_ 6144
#define O_ROWS_ 4096
#define NSPLIT_ 4

// ws layout (float offsets)
#define Q_OFF    0
#define KNEW_OFF (Q_OFF + B_*DIM_)
#define VNEW_OFF (KNEW_OFF + B_*NKV_*HD_)
#define AO_OFF   (VNEW_OFF + B_*NKV_*HD_)
#define PQKV_OFF (AO_OFF + B_*DIM_)
#define PO_OFF   (PQKV_OFF + KS_*QKV_ROWS_*B_)
#define OPART_OFF (PO_OFF + KS_*O_ROWS_*B_)
#define ML_OFF   (OPART_OFF + B_*NKV_*NSPLIT_*4*HD_)
// ML: B*NKV*NSPLIT*4 reps*2 floats

__device__ __forceinline__ void fma4(float4& a, const float4& x, float w) {
    a.x = fmaf(x.x, w, a.x); a.y = fmaf(x.y, w, a.y);
    a.z = fmaf(x.z, w, a.z); a.w = fmaf(x.w, w, a.w);
}

// C[b][row] partial = sum_{k in chunk} X[b][k] * W[row][k]
template<int NROWS>
__global__ __launch_bounds__(256) void gemm_split(
    const float* __restrict__ X, const float* __restrict__ W0,
    const float* __restrict__ W1, const float* __restrict__ W2,
    float* __restrict__ part)
{
    __shared__ float xs[32][36];
    __shared__ float wsh[32][132];
    const int rb = blockIdx.x, ks = blockIdx.y;
    const int row0 = rb * 128;
    const float* W; int wr0;
    if (NROWS == 4096 || row0 < 4096) { W = W0; wr0 = row0; }
    else if (row0 < 5120)             { W = W1; wr0 = row0 - 4096; }
    else                              { W = W2; wr0 = row0 - 5120; }
    const int tid = threadIdx.x;
    const int rt = tid & 31, bt = tid >> 5;
    float4 acc[4];
    acc[0] = acc[1] = acc[2] = acc[3] = make_float4(0.f,0.f,0.f,0.f);
    const int kc0 = ks * 256;
    const int xb = tid >> 3, xkq = tid & 7;
    for (int kt = 0; kt < 8; ++kt) {
        const int kc = kc0 + kt * 32;
        __syncthreads();
        {
            float4 v = *(const float4*)(X + xb * DIM_ + kc + xkq * 4);
            xs[xkq*4+0][xb] = v.x; xs[xkq*4+1][xb] = v.y;
            xs[xkq*4+2][xb] = v.z; xs[xkq*4+3][xb] = v.w;
        }
        #pragma unroll
        for (int j = 0; j < 4; ++j) {
            int f = tid + 256 * j;
            int r = f >> 3, kq = f & 7;
            float4 v = *(const float4*)(W + (wr0 + r) * DIM_ + kc + kq * 4);
            wsh[kq*4+0][r] = v.x; wsh[kq*4+1][r] = v.y;
            wsh[kq*4+2][r] = v.z; wsh[kq*4+3][r] = v.w;
        }
        __syncthreads();
        #pragma unroll
        for (int k = 0; k < 32; ++k) {
            float4 xv = *(const float4*)&xs[k][bt*4];
            float4 wv = *(const float4*)&wsh[k][rt*4];
            fma4(acc[0], xv, wv.x);
            fma4(acc[1], xv, wv.y);
            fma4(acc[2], xv, wv.z);
            fma4(acc[3], xv, wv.w);
        }
    }
    #pragma unroll
    for (int j = 0; j < 4; ++j) {
        const int row = row0 + rt * 4 + j;
        *(float4*)(part + (ks * NROWS + row) * 32 + bt * 4) = acc[j];
    }
}

__global__ __launch_bounds__(256) void reduce_rope(
    const float* __restrict__ part, const float* __restrict__ fc,
    const float* __restrict__ fs, float* __restrict__ qout,
    float* __restrict__ kout, float* __restrict__ vout)
{
    const int t = blockIdx.x * 256 + threadIdx.x;
    const int b = t & 31;
    const int row0 = (t >> 5) * 2;
    float s0 = 0.f, s1 = 0.f;
    #pragma unroll
    for (int ks = 0; ks < KS_; ++ks) {
        const float* p = part + (ks * QKV_ROWS_ + row0) * 32 + b;
        s0 += p[0];
        s1 += p[32];
    }
    if (row0 < 5120) {
        const int i = (row0 & 127) >> 1;
        const float c = fc[i], s = fs[i];
        const float o0 = s0 * c - s1 * s;
        const float o1 = s0 * s + s1 * c;
        if (row0 < 4096) {
            qout[b * 4096 + row0]     = o0;
            qout[b * 4096 + row0 + 1] = o1;
        } else {
            const int lr = row0 - 4096;
            kout[b * 1024 + lr]     = o0;
            kout[b * 1024 + lr + 1] = o1;
        }
    } else {
        const int lr = row0 - 5120;
        vout[b * 1024 + lr]     = s0;
        vout[b * 1024 + lr + 1] = s1;
    }
}

// split-T decode attention: block = (b, kv, sp) handles 512 t positions,
// writes unnormalized partial O + (m,l) per rep. 256 thr = 4 waves.
__global__ __launch_bounds__(256, 4) void attn_split(
    const float* __restrict__ q, const float* __restrict__ knew,
    const float* __restrict__ vnew, const float* __restrict__ ck,
    const float* __restrict__ cv, float* __restrict__ opart,
    float* __restrict__ ml)
{
    __shared__ float sct[512 * 4];   // [t][rep] scores then probs
    __shared__ float red[2048];      // [wave][rep][64 lanes] float2 partial O
    const int sp = blockIdx.x & 3;
    const int kv = (blockIdx.x >> 2) & 7;
    const int b  = blockIdx.x >> 5;
    const int tid = threadIdx.x;
    const int w  = tid >> 6;
    const int ln = tid & 63;
    const int t0 = sp * 512;
    const float scale = 0.08838834764831845f;  // 128^-0.5

    // ---- phase A: scores, duplicate-free K loads ----
    // lane = (tl row 0..3, dsl 16-seg); lane loads 32B of k row; q in regs
    const int tl = ln >> 4, dsl = ln & 15;
    float4 qr[4][2];
    #pragma unroll
    for (int r = 0; r < 4; ++r) {
        const float* qp = q + b * 4096 + (kv * 4 + r) * 128 + dsl * 8;
        qr[r][0] = *(const float4*)qp;
        qr[r][1] = *(const float4*)(qp + 4);
    }
    const float* ckb = ck + ((size_t)(b * 2048) * 8 + kv) * 128;
    const float* knb = knew + (b * 8 + kv) * 128 + dsl * 8;

    for (int tt = 0; tt < 32; tt += 4) {   // wave does 16 rows/iter, 8 loads in flight
        float4 ka[4][2];
        int ri[4];
        #pragma unroll
        for (int u = 0; u < 4; ++u) {
            ri[u] = w * 128 + (tt + u) * 4 + tl;
            const int gt = t0 + ri[u];
            const float* kp = (gt == 2047) ? knb
                              : (ckb + (size_t)gt * 1024 + dsl * 8);
            ka[u][0] = *(const float4*)kp;
            ka[u][1] = *(const float4*)(kp + 4);
        }
        #pragma unroll
        for (int u = 0; u < 4; ++u) {
            float d[4];
            #pragma unroll
            for (int r = 0; r < 4; ++r) {
                float t1 = ka[u][0].x*qr[r][0].x + ka[u][0].y*qr[r][0].y
                         + ka[u][0].z*qr[r][0].z + ka[u][0].w*qr[r][0].w;
                float t2 = ka[u][1].x*qr[r][1].x + ka[u][1].y*qr[r][1].y
                         + ka[u][1].z*qr[r][1].z + ka[u][1].w*qr[r][1].w;
                float dd = t1 + t2;
                dd += __shfl_xor(dd, 1);
                dd += __shfl_xor(dd, 2);
                dd += __shfl_xor(dd, 4);
                dd += __shfl_xor(dd, 8);
                d[r] = dd * scale;
            }
            if (dsl == 0)
                *(float4*)&sct[ri[u] * 4] = make_float4(d[0], d[1], d[2], d[3]);
        }
    }
    __syncthreads();

    // ---- phase B: per-split softmax; wave w handles rep w ----
    float vals[8];
    #pragma unroll
    for (int j = 0; j < 8; ++j)
        vals[j] = sct[(j * 64 + ln) * 4 + w];
    float m = vals[0];
    #pragma unroll
    for (int j = 1; j < 8; ++j) m = fmaxf(m, vals[j]);
    #pragma unroll
    for (int o = 1; o < 64; o <<= 1)
        m = fmaxf(m, __shfl_xor(m, o));
    float l = 0.f;
    #pragma unroll
    for (int j = 0; j < 8; ++j) {
        const float p = __expf(vals[j] - m);
        sct[(j * 64 + ln) * 4 + w] = p;
        l += p;
    }
    #pragma unroll
    for (int o = 1; o < 64; o <<= 1)
        l += __shfl_xor(l, o);
    if (ln == 0) {
        const int idx = ((b * 8 + kv) * 4 + sp) * 8 + w * 2;
        ml[idx]     = m;
        ml[idx + 1] = l;
    }
    __syncthreads();

    // ---- phase C: partial O = P V, duplicate-free float2 V loads ----
    // lane covers d floats [ln*2, ln*2+2); wave w handles rows w*128..+127
    float2 acc[4];
    #pragma unroll
    for (int r = 0; r < 4; ++r) acc[r] = make_float2(0.f, 0.f);
    const float* cvb = cv + ((size_t)(b * 2048) * 8 + kv) * 128 + ln * 2;
    const float* vnb = vnew + (b * 8 + kv) * 128 + ln * 2;
    for (int j = 0; j < 128; j += 8) {
        float2 vv[8];
        #pragma unroll
        for (int u = 0; u < 8; ++u) {
            const int gt = t0 + w * 128 + j + u;
            const float* vp = (gt == 2047) ? vnb : (cvb + (size_t)gt * 1024);
            vv[u] = *(const float2*)vp;
        }
        #pragma unroll
        for (int u = 0; u < 8; ++u) {
            const int ri = w * 128 + j + u;
            const float4 p4 = *(const float4*)&sct[ri * 4];  // broadcast
            acc[0].x = fmaf(vv[u].x, p4.x, acc[0].x);
            acc[0].y = fmaf(vv[u].y, p4.x, acc[0].y);
            acc[1].x = fmaf(vv[u].x, p4.y, acc[1].x);
            acc[1].y = fmaf(vv[u].y, p4.y, acc[1].y);
            acc[2].x = fmaf(vv[u].x, p4.z, acc[2].x);
            acc[2].y = fmaf(vv[u].y, p4.z, acc[2].y);
            acc[3].x = fmaf(vv[u].x, p4.w, acc[3].x);
            acc[3].y = fmaf(vv[u].y, p4.w, acc[3].y);
        }
    }
    #pragma unroll
    for (int r = 0; r < 4; ++r)
        *(float2*)&red[((w * 4 + r) * 64 + ln) * 2] = acc[r];
    __syncthreads();
    {
        const int r = tid >> 6, dd = tid & 63;
        float2 s = make_float2(0.f, 0.f);
        #pragma unroll
        for (int ww = 0; ww < 4; ++ww) {
            const float2 v = *(const float2*)&red[((ww * 4 + r) * 64 + dd) * 2];
            s.x += v.x; s.y += v.y;
        }
        const int ob = (((b * 8 + kv) * 4 + sp) * 4 + r) * 128 + dd * 2;
        *(float2*)&opart[ob] = s;
    }
}

// merge NSPLIT_ partials with log-sum-exp weights
__global__ __launch_bounds__(128) void attn_merge(
    const float* __restrict__ opart, const float* __restrict__ ml,
    float* __restrict__ ao)
{
    const int bk = blockIdx.x;          // b*8+kv
    const int tid = threadIdx.x;
    const int r = tid >> 5, dq = tid & 31;
    float m[4], l[4];
    #pragma unroll
    for (int sp = 0; sp < 4; ++sp) {
        m[sp] = ml[(bk * 4 + sp) * 8 + r * 2];
        l[sp] = ml[(bk * 4 + sp) * 8 + r * 2 + 1];
    }
    const float M = fmaxf(fmaxf(m[0], m[1]), fmaxf(m[2], m[3]));
    float wgt[4], L = 0.f;
    #pragma unroll
    for (int sp = 0; sp < 4; ++sp) {
        wgt[sp] = __expf(m[sp] - M);
        L += l[sp] * wgt[sp];
    }
    float4 o = make_float4(0.f, 0.f, 0.f, 0.f);
    #pragma unroll
    for (int sp = 0; sp < 4; ++sp) {
        const float4 v = *(const float4*)&opart[((bk * 4 + sp) * 4 + r) * 128 + dq * 4];
        fma4(o, v, wgt[sp]);
    }
    const float inv = 1.f / L;
    o.x *= inv; o.y *= inv; o.z *= inv; o.w *= inv;
    *(float4*)&ao[bk * 512 + r * 128 + dq * 4] = o;
}

__global__ __launch_bounds__(256) void reduce_out(
    const float* __restrict__ part, float* __restrict__ out)
{
    const int t = blockIdx.x * 256 + threadIdx.x;
    const int b = t & 31, row = t >> 5;
    float s = 0.f;
    #pragma unroll
    for (int ks = 0; ks < KS_; ++ks)
        s += part[(ks * O_ROWS_ + row) * 32 + b];
    out[b * 4096 + row] = s;
}

extern "C" void kernel_launch(void* const* d_in, const int* in_sizes, int n_in,
                              void* d_out, int out_size, void* d_ws, size_t ws_size,
                              hipStream_t stream)
{
    const float* x  = (const float*)d_in[0];
    const float* fc = (const float*)d_in[1];
    const float* fs = (const float*)d_in[2];
    const float* wq = (const float*)d_in[3];
    const float* wk = (const float*)d_in[4];
    const float* wv = (const float*)d_in[5];
    const float* wo = (const float*)d_in[6];
    const float* ck = (const float*)d_in[7];
    const float* cv = (const float*)d_in[8];
    float* ws    = (float*)d_ws;
    float* q     = ws + Q_OFF;
    float* knew  = ws + KNEW_OFF;
    float* vnew  = ws + VNEW_OFF;
    float* ao    = ws + AO_OFF;
    float* pqkv  = ws + PQKV_OFF;
    float* po    = ws + PO_OFF;
    float* opart = ws + OPART_OFF;
    float* mlp   = ws + ML_OFF;

    gemm_split<QKV_ROWS_><<<dim3(48, 16), 256, 0, stream>>>(x, wq, wk, wv, pqkv);
    reduce_rope<<<384, 256, 0, stream>>>(pqkv, fc, fs, q, knew, vnew);
    attn_split<<<1024, 256, 0, stream>>>(q, knew, vnew, ck, cv, opart, mlp);
    attn_merge<<<256, 128, 0, stream>>>(opart, mlp, ao);
    gemm_split<O_ROWS_><<<dim3(32, 16), 256, 0, stream>>>(ao, wo, wo, wo, po);
    reduce_out<<<512, 256, 0, stream>>>(po, (float*)d_out);
}